// Round 1
// baseline (152.601 us; speedup 1.0000x reference)
//
#include <hip/hip_runtime.h>
#include <stdint.h>

#define NCOL 16

// ---- ordered-uint mapping for float atomic min/max ----
__device__ __forceinline__ uint32_t fkey(float f) {
    uint32_t u = __float_as_uint(f);
    return (u & 0x80000000u) ? ~u : (u | 0x80000000u);
}
__device__ __forceinline__ float fkey_dec(uint32_t k) {
    uint32_t u = (k & 0x80000000u) ? (k ^ 0x80000000u) : ~k;
    return __uint_as_float(u);
}

// ws layout: [0..15] = min keys, [16..31] = max keys
__global__ void init_minmax(uint32_t* mm) {
    int t = threadIdx.x;
    if (t < NCOL)            mm[t] = fkey(INFINITY);    // atomicMin target
    else if (t < 2 * NCOL)   mm[t] = fkey(-INFINITY);   // atomicMax target
}

// Column-wise min/max over x[N,16] row-major, read as float4.
// Global float4 index i covers columns (4*i)%16 .. +3; with stride a multiple
// of 4 float4s, each thread's column group g=(tid&3)*4 is loop-invariant.
__global__ void __launch_bounds__(256) colreduce(const float4* __restrict__ x,
                                                 uint32_t* __restrict__ mm, int n4) {
    int tid = blockIdx.x * blockDim.x + threadIdx.x;
    int stride = gridDim.x * blockDim.x;   // 256-thread blocks -> multiple of 4
    float mn0 = INFINITY, mn1 = INFINITY, mn2 = INFINITY, mn3 = INFINITY;
    float mx0 = -INFINITY, mx1 = -INFINITY, mx2 = -INFINITY, mx3 = -INFINITY;
    for (int i = tid; i < n4; i += stride) {
        float4 v = x[i];
        mn0 = fminf(mn0, v.x); mx0 = fmaxf(mx0, v.x);
        mn1 = fminf(mn1, v.y); mx1 = fmaxf(mx1, v.y);
        mn2 = fminf(mn2, v.z); mx2 = fmaxf(mx2, v.z);
        mn3 = fminf(mn3, v.w); mx3 = fmaxf(mx3, v.w);
    }
    // Butterfly across the 16 lanes sharing the same (lane&3) column group.
    #pragma unroll
    for (int off = 4; off < 64; off <<= 1) {
        mn0 = fminf(mn0, __shfl_xor(mn0, off)); mx0 = fmaxf(mx0, __shfl_xor(mx0, off));
        mn1 = fminf(mn1, __shfl_xor(mn1, off)); mx1 = fmaxf(mx1, __shfl_xor(mx1, off));
        mn2 = fminf(mn2, __shfl_xor(mn2, off)); mx2 = fmaxf(mx2, __shfl_xor(mx2, off));
        mn3 = fminf(mn3, __shfl_xor(mn3, off)); mx3 = fmaxf(mx3, __shfl_xor(mx3, off));
    }
    __shared__ float smn[4][NCOL], smx[4][NCOL];
    int wave = threadIdx.x >> 6;
    int lane = threadIdx.x & 63;
    if (lane < 4) {           // lane l holds the full wave reduction for group l
        int g = lane * 4;
        smn[wave][g + 0] = mn0; smx[wave][g + 0] = mx0;
        smn[wave][g + 1] = mn1; smx[wave][g + 1] = mx1;
        smn[wave][g + 2] = mn2; smx[wave][g + 2] = mx2;
        smn[wave][g + 3] = mn3; smx[wave][g + 3] = mx3;
    }
    __syncthreads();
    if (threadIdx.x < NCOL) {
        int c = threadIdx.x;
        float m = fminf(fminf(smn[0][c], smn[1][c]), fminf(smn[2][c], smn[3][c]));
        float M = fmaxf(fmaxf(smx[0][c], smx[1][c]), fmaxf(smx[2][c], smx[3][c]));
        atomicMin(&mm[c], fkey(m));
        atomicMax(&mm[NCOL + c], fkey(M));
    }
}

// out = w0*xn + w1*xn^2 + w2*xn^3 + w3*exp(xn) + w4*log(|xn|+1) + w5*sqrt(|xn|)
//     + w6*tanh(xn) + w7*sin(xn) + w8*|xn| + bias      (xn in [-1,1] -> clips no-op)
__device__ __forceinline__ float eval_basis(float xn, const float* w, float b) {
    float ax = fabsf(xn);
    float x2 = xn * xn;
    float x3 = x2 * xn;
    float e  = __expf(xn);
    float e2 = e * e;                               // exp(2*xn)
    float t  = 1.0f - 2.0f * __frcp_rn(e2 + 1.0f);  // tanh
    float l  = __logf(ax + 1.0f);
    float sq = __fsqrt_rn(ax);
    float sn = __sinf(xn);
    float r = b;
    r = fmaf(w[0], xn, r);
    r = fmaf(w[1], x2, r);
    r = fmaf(w[2], x3, r);
    r = fmaf(w[3], e,  r);
    r = fmaf(w[4], l,  r);
    r = fmaf(w[5], sq, r);
    r = fmaf(w[6], t,  r);
    r = fmaf(w[7], sn, r);
    r = fmaf(w[8], ax, r);
    return r;
}

__global__ void __launch_bounds__(256) feature_kernel(const float4* __restrict__ x,
                                                      float4* __restrict__ out,
                                                      const uint32_t* __restrict__ mm,
                                                      const float* __restrict__ wts,
                                                      const float* __restrict__ bias,
                                                      int n4) {
    __shared__ float s_scale[NCOL], s_off[NCOL], s_w[9];
    if (threadIdx.x < NCOL) {
        float mn = fkey_dec(mm[threadIdx.x]);
        float mx = fkey_dec(mm[NCOL + threadIdx.x]);
        float r = mx - mn;
        if (r == 0.0f) r = 1.0f;
        s_scale[threadIdx.x] = 2.0f / r;
        s_off[threadIdx.x]   = -2.0f * mn / r - 1.0f;
    }
    if (threadIdx.x < 9) s_w[threadIdx.x] = wts[threadIdx.x];
    __syncthreads();

    int tid = blockIdx.x * blockDim.x + threadIdx.x;
    if (tid >= n4) return;
    int g = (tid & 3) * 4;                // this thread's 4 columns
    float sc0 = s_scale[g + 0], of0 = s_off[g + 0];
    float sc1 = s_scale[g + 1], of1 = s_off[g + 1];
    float sc2 = s_scale[g + 2], of2 = s_off[g + 2];
    float sc3 = s_scale[g + 3], of3 = s_off[g + 3];
    float w[9];
    #pragma unroll
    for (int k = 0; k < 9; ++k) w[k] = s_w[k];
    float b = bias[0];

    float4 v = x[tid];
    float4 o;
    o.x = eval_basis(fmaf(v.x, sc0, of0), w, b);
    o.y = eval_basis(fmaf(v.y, sc1, of1), w, b);
    o.z = eval_basis(fmaf(v.z, sc2, of2), w, b);
    o.w = eval_basis(fmaf(v.w, sc3, of3), w, b);
    out[tid] = o;
}

extern "C" void kernel_launch(void* const* d_in, const int* in_sizes, int n_in,
                              void* d_out, int out_size, void* d_ws, size_t ws_size,
                              hipStream_t stream) {
    const float* x    = (const float*)d_in[0];
    const float* wts  = (const float*)d_in[1];
    const float* bias = (const float*)d_in[2];
    float* out = (float*)d_out;
    uint32_t* mm = (uint32_t*)d_ws;

    int n  = in_sizes[0];       // N * 16 elements
    int n4 = n / 4;             // exact: 16e6 / 4

    init_minmax<<<1, 64, 0, stream>>>(mm);
    colreduce<<<2048, 256, 0, stream>>>((const float4*)x, mm, n4);
    int blocks = (n4 + 255) / 256;
    feature_kernel<<<blocks, 256, 0, stream>>>((const float4*)x, (float4*)out, mm,
                                               wts, bias, n4);
}

// Round 3
// 149.639 us; speedup vs baseline: 1.0198x; 1.0198x over previous
//
#include <hip/hip_runtime.h>
#include <stdint.h>

#define NCOL 16
typedef float v4f __attribute__((ext_vector_type(4)));

// ---- ordered-uint mapping for float atomic min/max ----
__device__ __forceinline__ uint32_t fkey(float f) {
    uint32_t u = __float_as_uint(f);
    return (u & 0x80000000u) ? ~u : (u | 0x80000000u);
}
__device__ __forceinline__ float fkey_dec(uint32_t k) {
    uint32_t u = (k & 0x80000000u) ? (k ^ 0x80000000u) : ~k;
    return __uint_as_float(u);
}

// ws layout: [0..15] = min keys, [16..31] = max keys
__global__ void init_minmax(uint32_t* mm) {
    int t = threadIdx.x;
    if (t < NCOL)            mm[t] = fkey(INFINITY);    // atomicMin target
    else if (t < 2 * NCOL)   mm[t] = fkey(-INFINITY);   // atomicMax target
}

// Column-wise min/max over x[N,16] row-major, read as float4.
// Global float4 index i covers columns (4*i)%16 .. +3; with stride a multiple
// of 4 float4s, each thread's column group g=(tid&3)*4 is loop-invariant.
__global__ void __launch_bounds__(256) colreduce(const v4f* __restrict__ x,
                                                 uint32_t* __restrict__ mm, int n4) {
    int tid = blockIdx.x * blockDim.x + threadIdx.x;
    int stride = gridDim.x * blockDim.x;   // 256-thread blocks -> multiple of 4
    float mn0 = INFINITY, mn1 = INFINITY, mn2 = INFINITY, mn3 = INFINITY;
    float mx0 = -INFINITY, mx1 = -INFINITY, mx2 = -INFINITY, mx3 = -INFINITY;
    for (int i = tid; i < n4; i += stride) {
        v4f v = x[i];   // regular load: populates L2/L3 so pass 2 hits L3
        mn0 = fminf(mn0, v.x); mx0 = fmaxf(mx0, v.x);
        mn1 = fminf(mn1, v.y); mx1 = fmaxf(mx1, v.y);
        mn2 = fminf(mn2, v.z); mx2 = fmaxf(mx2, v.z);
        mn3 = fminf(mn3, v.w); mx3 = fmaxf(mx3, v.w);
    }
    // Butterfly across the 16 lanes sharing the same (lane&3) column group.
    #pragma unroll
    for (int off = 4; off < 64; off <<= 1) {
        mn0 = fminf(mn0, __shfl_xor(mn0, off)); mx0 = fmaxf(mx0, __shfl_xor(mx0, off));
        mn1 = fminf(mn1, __shfl_xor(mn1, off)); mx1 = fmaxf(mx1, __shfl_xor(mx1, off));
        mn2 = fminf(mn2, __shfl_xor(mn2, off)); mx2 = fmaxf(mx2, __shfl_xor(mx2, off));
        mn3 = fminf(mn3, __shfl_xor(mn3, off)); mx3 = fmaxf(mx3, __shfl_xor(mx3, off));
    }
    __shared__ float smn[4][NCOL], smx[4][NCOL];
    int wave = threadIdx.x >> 6;
    int lane = threadIdx.x & 63;
    if (lane < 4) {           // lane l holds the full wave reduction for group l
        int g = lane * 4;
        smn[wave][g + 0] = mn0; smx[wave][g + 0] = mx0;
        smn[wave][g + 1] = mn1; smx[wave][g + 1] = mx1;
        smn[wave][g + 2] = mn2; smx[wave][g + 2] = mx2;
        smn[wave][g + 3] = mn3; smx[wave][g + 3] = mx3;
    }
    __syncthreads();
    if (threadIdx.x < NCOL) {
        int c = threadIdx.x;
        float m = fminf(fminf(smn[0][c], smn[1][c]), fminf(smn[2][c], smn[3][c]));
        float M = fmaxf(fmaxf(smx[0][c], smx[1][c]), fmaxf(smx[2][c], smx[3][c]));
        atomicMin(&mm[c], fkey(m));
        atomicMax(&mm[NCOL + c], fkey(M));
    }
}

// out = w0*xn + w1*xn^2 + w2*xn^3 + w3*exp(xn) + w4*log(|xn|+1) + w5*sqrt(|xn|)
//     + w6*tanh(xn) + w7*sin(xn) + w8*|xn| + bias      (xn in [-1,1] -> clips no-op)
__device__ __forceinline__ float eval_basis(float xn, const float* w, float b) {
    float ax = fabsf(xn);
    float x2 = xn * xn;
    float x3 = x2 * xn;
    float e  = __expf(xn);
    float e2 = e * e;                               // exp(2*xn)
    float t  = 1.0f - 2.0f * __frcp_rn(e2 + 1.0f);  // tanh
    float l  = __logf(ax + 1.0f);
    float sq = __fsqrt_rn(ax);
    float sn = __sinf(xn);
    float r = b;
    r = fmaf(w[0], xn, r);
    r = fmaf(w[1], x2, r);
    r = fmaf(w[2], x3, r);
    r = fmaf(w[3], e,  r);
    r = fmaf(w[4], l,  r);
    r = fmaf(w[5], sq, r);
    r = fmaf(w[6], t,  r);
    r = fmaf(w[7], sn, r);
    r = fmaf(w[8], ax, r);
    return r;
}

__global__ void __launch_bounds__(256) feature_kernel(const v4f* __restrict__ x,
                                                      v4f* __restrict__ out,
                                                      const uint32_t* __restrict__ mm,
                                                      const float* __restrict__ wts,
                                                      const float* __restrict__ bias,
                                                      int n4) {
    __shared__ float s_scale[NCOL], s_off[NCOL], s_w[9];
    if (threadIdx.x < NCOL) {
        float mn = fkey_dec(mm[threadIdx.x]);
        float mx = fkey_dec(mm[NCOL + threadIdx.x]);
        float r = mx - mn;
        if (r == 0.0f) r = 1.0f;
        s_scale[threadIdx.x] = 2.0f / r;
        s_off[threadIdx.x]   = -2.0f * mn / r - 1.0f;
    }
    if (threadIdx.x < 9) s_w[threadIdx.x] = wts[threadIdx.x];
    __syncthreads();

    int tid = blockIdx.x * blockDim.x + threadIdx.x;
    int stride = gridDim.x * blockDim.x;   // multiple of 4 -> column group fixed
    int g = (tid & 3) * 4;                 // this thread's 4 columns
    float sc0 = s_scale[g + 0], of0 = s_off[g + 0];
    float sc1 = s_scale[g + 1], of1 = s_off[g + 1];
    float sc2 = s_scale[g + 2], of2 = s_off[g + 2];
    float sc3 = s_scale[g + 3], of3 = s_off[g + 3];
    float w[9];
    #pragma unroll
    for (int k = 0; k < 9; ++k) w[k] = s_w[k];
    float b = bias[0];

    for (int i = tid; i < n4; i += stride) {
        v4f v = x[i];
        v4f o;
        o.x = eval_basis(fmaf(v.x, sc0, of0), w, b);
        o.y = eval_basis(fmaf(v.y, sc1, of1), w, b);
        o.z = eval_basis(fmaf(v.z, sc2, of2), w, b);
        o.w = eval_basis(fmaf(v.w, sc3, of3), w, b);
        // nontemporal: out is never re-read; don't evict x from L2/L3
        __builtin_nontemporal_store(o, &out[i]);
    }
}

extern "C" void kernel_launch(void* const* d_in, const int* in_sizes, int n_in,
                              void* d_out, int out_size, void* d_ws, size_t ws_size,
                              hipStream_t stream) {
    const float* x    = (const float*)d_in[0];
    const float* wts  = (const float*)d_in[1];
    const float* bias = (const float*)d_in[2];
    float* out = (float*)d_out;
    uint32_t* mm = (uint32_t*)d_ws;

    int n  = in_sizes[0];       // N * 16 elements
    int n4 = n / 4;             // exact: 16e6 / 4

    init_minmax<<<1, 64, 0, stream>>>(mm);
    colreduce<<<2048, 256, 0, stream>>>((const v4f*)x, mm, n4);
    feature_kernel<<<4096, 256, 0, stream>>>((const v4f*)x, (v4f*)out, mm,
                                             wts, bias, n4);
}